// Round 7
// baseline (297.881 us; speedup 1.0000x reference)
//
#include <hip/hip_runtime.h>
#include <cstdint>
#include <cstddef>

// ---------------------------------------------------------------------------
// SelfAttention (B=4, S=2048, D=1024, single head, causal) on gfx950.
// Round 5/7: 2-phase double-buffered GEMM core (T3 minimum recipe): stage(t+1)
// issued BEFORE compute(t), ONE __syncthreads per K-step -> global-load
// latency hidden under ds_read+MFMA. Triangular-compacted k_scores grid.
// Pipeline: conv -> Q,K GEMM -> V^T GEMM -> tile-softmax scores -> combine
// -> PV GEMM (with F fold) -> out.
// ---------------------------------------------------------------------------

typedef __attribute__((ext_vector_type(8))) __bf16 bf16x8;
typedef __attribute__((ext_vector_type(4))) float f32x4;
typedef __attribute__((ext_vector_type(4))) float float4v;
typedef __attribute__((ext_vector_type(8))) unsigned short u16x8;
typedef __attribute__((ext_vector_type(4))) unsigned short u16x4;

#define DEVI static __device__ __forceinline__

static constexpr int SS = 2048;
static constexpr int DD = 1024;
static constexpr float SCALE = 0.03125f;  // 1/sqrt(1024)

DEVI unsigned short f2bf(float f) {
  unsigned int u = __builtin_bit_cast(unsigned int, f);
  u += 0x7fffu + ((u >> 16) & 1u);  // RNE
  return (unsigned short)(u >> 16);
}
DEVI float bf2f(unsigned short h) {
  unsigned int u = ((unsigned int)h) << 16;
  return __builtin_bit_cast(float, u);
}

DEVI void gload16(const void* g, void* l) {
  __builtin_amdgcn_global_load_lds(
      (const __attribute__((address_space(1))) unsigned int*)g,
      (__attribute__((address_space(3))) unsigned int*)l, 16, 0, 0);
}

// ---- 2-phase double-buffered 128x128-tile GEMM, 512 thr / 8 waves (2x4) ---
// C += A[M,K] * Bt[N,K]^T, bf16 in, f32 acc. Wave tile 64x32 -> acc[4][2].
// As/Bs: 8192 shorts each (two 4096-short buffers). K multiple of 32.
DEVI void gemm2ph(const unsigned short* __restrict__ A,
                  const unsigned short* __restrict__ Bt,
                  int lda, int ldb, int m0, int n0, int K,
                  unsigned short* As, unsigned short* Bs,
                  f32x4 acc[4][2]) {
  const int t = threadIdx.x;
  const int l = t & 63, w = t >> 6;
  const int wr = w >> 2, wc = w & 3;
  const int srow = t >> 2;          // staging row 0..127
  const int scol = (t & 3) * 8;     // staging col offset (elems)
  const unsigned short* ga = A + (size_t)(m0 + srow) * lda + scol;
  const unsigned short* gb = Bt + (size_t)(n0 + srow) * ldb + scol;
  unsigned short* la = As + t * 8;  // linear LDS dest (wave-uniform + lane*16B)
  unsigned short* lb = Bs + t * 8;
  const int aoff = (wr * 64 + (l & 15)) * 32 + (l >> 4) * 8;
  const int boff = (wc * 32 + (l & 15)) * 32 + (l >> 4) * 8;
  const int nt = K >> 5;
  // prologue: stage tile 0 into buffer 0
  gload16(ga, la);
  gload16(gb, lb);
  __syncthreads();
  int cur = 0;
  for (int ti = 0; ti < nt; ++ti) {
    if (ti + 1 < nt) {              // prefetch next tile into other buffer
      const int kk = (ti + 1) << 5;
      gload16(ga + kk, la + (cur ^ 1) * 4096);
      gload16(gb + kk, lb + (cur ^ 1) * 4096);
    }
    const unsigned short* Ab = As + cur * 4096;
    const unsigned short* Bb = Bs + cur * 4096;
    bf16x8 av[4], bv[2];
#pragma unroll
    for (int i = 0; i < 4; ++i) av[i] = *(const bf16x8*)(Ab + aoff + i * 512);
#pragma unroll
    for (int i = 0; i < 2; ++i) bv[i] = *(const bf16x8*)(Bb + boff + i * 512);
#pragma unroll
    for (int mi = 0; mi < 4; ++mi)
#pragma unroll
      for (int ni = 0; ni < 2; ++ni)
        acc[mi][ni] = __builtin_amdgcn_mfma_f32_16x16x32_bf16(
            av[mi], bv[ni], acc[mi][ni], 0, 0, 0);
    __syncthreads();  // vmcnt(0)+lgkmcnt(0)+barrier: prefetch landed, reads done
    cur ^= 1;
  }
}

// ---- prep: x fp32 -> bf16 -------------------------------------------------
__global__ __launch_bounds__(256) void k_conv_x(const float* __restrict__ x,
                                                unsigned short* __restrict__ xb) {
  size_t i = ((size_t)blockIdx.x * 256 + threadIdx.x) * 4;
  float4v v = *(const float4v*)(x + i);
  u16x4 o;
#pragma unroll
  for (int j = 0; j < 4; ++j) o[j] = f2bf(v[j]);
  *(u16x4*)(xb + i) = o;
}

// ---- prep: W [k][n] fp32 -> Wt [n][k] bf16 (3 matrices) -------------------
__global__ __launch_bounds__(256) void k_prep_w(const float* __restrict__ Wq,
                                                const float* __restrict__ Wk,
                                                const float* __restrict__ Wv,
                                                unsigned short* __restrict__ Wt) {
  const int z = blockIdx.z;
  const float* W = (z == 0) ? Wq : (z == 1) ? Wk : Wv;
  unsigned short* O = Wt + (size_t)z * DD * DD;
  const int c0 = blockIdx.x * 64, r0 = blockIdx.y * 64;
  __shared__ unsigned short T[64][72];
  const int t = threadIdx.x;
#pragma unroll
  for (int i = 0; i < 4; ++i) {
    int idx = t + i * 256;          // 0..1023
    int row = idx >> 4;             // 0..63
    int c4 = (idx & 15) * 4;
    float4v v = *(const float4v*)(W + (size_t)(r0 + row) * DD + c0 + c4);
#pragma unroll
    for (int j = 0; j < 4; ++j) T[row][c4 + j] = f2bf(v[j]);
  }
  __syncthreads();
#pragma unroll
  for (int i = 0; i < 2; ++i) {
    int idx = t + i * 256;          // 0..511
    int n = idx >> 3;               // 0..63
    int g = (idx & 7) * 8;          // k group
    u16x8 u;
#pragma unroll
    for (int j = 0; j < 8; ++j) u[j] = T[g + j][n];
    *(u16x8*)(O + (size_t)(c0 + n) * DD + r0 + g) = u;
  }
}

// ---- Q and K projections: C[m][n] = x[m][:]*Wt[n][:] + bias[n] ------------
__global__ __launch_bounds__(512, 4) void k_qk_gemm(
    const unsigned short* __restrict__ xb,
    const unsigned short* __restrict__ Wqt,
    const unsigned short* __restrict__ Wkt,
    const float* __restrict__ bq, const float* __restrict__ bk,
    unsigned short* __restrict__ qb, unsigned short* __restrict__ kb) {
  __shared__ unsigned short As[8192], Bs[8192];
  const int z = blockIdx.z;
  const unsigned short* Bt = z ? Wkt : Wqt;
  const float* bias = z ? bk : bq;
  unsigned short* C = z ? kb : qb;
  const int m0 = blockIdx.x * 128, n0 = blockIdx.y * 128;
  f32x4 acc[4][2];
#pragma unroll
  for (int i = 0; i < 4; ++i)
#pragma unroll
    for (int j = 0; j < 2; ++j) acc[i][j] = f32x4{0.f, 0.f, 0.f, 0.f};
  gemm2ph(xb, Bt, DD, DD, m0, n0, DD, As, Bs, acc);
  const int t = threadIdx.x, l = t & 63, w = t >> 6, wr = w >> 2, wc = w & 3;
  const int fr = (l >> 4) * 4, fc = l & 15;
#pragma unroll
  for (int mi = 0; mi < 4; ++mi)
#pragma unroll
    for (int ni = 0; ni < 2; ++ni) {
      int gc = n0 + wc * 32 + ni * 16 + fc;
      float bv_ = bias[gc];
#pragma unroll
      for (int r = 0; r < 4; ++r) {
        int gr = m0 + wr * 64 + mi * 16 + fr + r;
        C[(size_t)gr * DD + gc] = f2bf(acc[mi][ni][r] + bv_);
      }
    }
}

// ---- V^T: C[d][s] = Wvt[d][:] * x[b][s][:] + bv[d]  (per batch) -----------
__global__ __launch_bounds__(512, 4) void k_vt_gemm(
    const unsigned short* __restrict__ Wvt,
    const unsigned short* __restrict__ xb,
    const float* __restrict__ bv, unsigned short* __restrict__ vt) {
  __shared__ unsigned short As[8192], Bs[8192];
  const int b = blockIdx.z;
  const int m0 = blockIdx.x * 128;  // d
  const int n0 = blockIdx.y * 128;  // s
  f32x4 acc[4][2];
#pragma unroll
  for (int i = 0; i < 4; ++i)
#pragma unroll
    for (int j = 0; j < 2; ++j) acc[i][j] = f32x4{0.f, 0.f, 0.f, 0.f};
  gemm2ph(Wvt, xb + (size_t)b * SS * DD, DD, DD, m0, n0, DD, As, Bs, acc);
  unsigned short* C = vt + (size_t)b * DD * SS;
  const int t = threadIdx.x, l = t & 63, w = t >> 6, wr = w >> 2, wc = w & 3;
  const int fr = (l >> 4) * 4, fc = l & 15;
#pragma unroll
  for (int mi = 0; mi < 4; ++mi)
#pragma unroll
    for (int ni = 0; ni < 2; ++ni) {
      int gc = n0 + wc * 32 + ni * 16 + fc;
#pragma unroll
      for (int r = 0; r < 4; ++r) {
        int gr = m0 + wr * 64 + mi * 16 + fr + r;
        C[(size_t)gr * SS + gc] = f2bf(acc[mi][ni][r] + bv[gr]);
      }
    }
}

// ---- scores: per (q-tile,k-tile), S=QK^T*scale, causal mask, tile softmax -
// Triangular-compacted grid: blockIdx.x = pair index p -> (qt, kt), kt<=qt.
// writes P_prov = exp(s - m_tile) (bf16) and per-row (m_tile, l_tile).
__global__ __launch_bounds__(512, 4) void k_scores(
    const unsigned short* __restrict__ qb,
    const unsigned short* __restrict__ kb,
    unsigned short* __restrict__ P,
    float* __restrict__ mT, float* __restrict__ lT) {
  const int p = blockIdx.x, b = blockIdx.z;
  int qt = (int)((sqrtf(8.f * (float)p + 1.f) - 1.f) * 0.5f);
  while ((qt + 1) * (qt + 2) / 2 <= p) ++qt;
  while (qt * (qt + 1) / 2 > p) --qt;
  const int kt = p - qt * (qt + 1) / 2;
  __shared__ unsigned short As[8192], Bs[8192];
  __shared__ float redm[4][128];
  __shared__ float redl[4][128];
  f32x4 acc[4][2];
#pragma unroll
  for (int i = 0; i < 4; ++i)
#pragma unroll
    for (int j = 0; j < 2; ++j) acc[i][j] = f32x4{0.f, 0.f, 0.f, 0.f};
  const unsigned short* qp = qb + (size_t)b * SS * DD;
  const unsigned short* kp = kb + (size_t)b * SS * DD;
  gemm2ph(qp, kp, DD, DD, qt * 128, kt * 128, DD, As, Bs, acc);

  const int t = threadIdx.x, l = t & 63, w = t >> 6, wr = w >> 2, wc = w & 3;
  const int fr = (l >> 4) * 4, fc = l & 15;
  const bool diag = (kt == qt);
  // scale + causal mask in place (local coords suffice: tiles share offset)
#pragma unroll
  for (int mi = 0; mi < 4; ++mi)
#pragma unroll
    for (int ni = 0; ni < 2; ++ni) {
      int lc = wc * 32 + ni * 16 + fc;
#pragma unroll
      for (int r = 0; r < 4; ++r) {
        int lr = wr * 64 + mi * 16 + fr + r;
        float s = acc[mi][ni][r] * SCALE;
        if (diag && lc > lr) s = -INFINITY;
        acc[mi][ni][r] = s;
      }
    }
  // per-row tile max across this wave's 32-col slice
  float rmax[4][4];
#pragma unroll
  for (int mi = 0; mi < 4; ++mi)
#pragma unroll
    for (int r = 0; r < 4; ++r)
      rmax[mi][r] = fmaxf(acc[mi][0][r], acc[mi][1][r]);
#pragma unroll
  for (int d = 1; d < 16; d <<= 1)
#pragma unroll
    for (int mi = 0; mi < 4; ++mi)
#pragma unroll
      for (int r = 0; r < 4; ++r)
        rmax[mi][r] = fmaxf(rmax[mi][r], __shfl_xor(rmax[mi][r], d));
  if ((l & 15) == 0) {
#pragma unroll
    for (int mi = 0; mi < 4; ++mi)
#pragma unroll
      for (int r = 0; r < 4; ++r)
        redm[wc][wr * 64 + mi * 16 + fr + r] = rmax[mi][r];
  }
  __syncthreads();
  float mtv[4][4];
#pragma unroll
  for (int mi = 0; mi < 4; ++mi)
#pragma unroll
    for (int r = 0; r < 4; ++r) {
      int row_l = wr * 64 + mi * 16 + fr + r;
      mtv[mi][r] = fmaxf(fmaxf(redm[0][row_l], redm[1][row_l]),
                         fmaxf(redm[2][row_l], redm[3][row_l]));
    }
  // P = exp(s - m_tile), row sums
  float rsum[4][4];
#pragma unroll
  for (int mi = 0; mi < 4; ++mi)
#pragma unroll
    for (int ni = 0; ni < 2; ++ni)
#pragma unroll
      for (int r = 0; r < 4; ++r) {
        float pv = __expf(acc[mi][ni][r] - mtv[mi][r]);
        acc[mi][ni][r] = pv;
        if (ni == 0) rsum[mi][r] = pv; else rsum[mi][r] += pv;
      }
#pragma unroll
  for (int d = 1; d < 16; d <<= 1)
#pragma unroll
    for (int mi = 0; mi < 4; ++mi)
#pragma unroll
      for (int r = 0; r < 4; ++r)
        rsum[mi][r] += __shfl_xor(rsum[mi][r], d);
  if ((l & 15) == 0) {
#pragma unroll
    for (int mi = 0; mi < 4; ++mi)
#pragma unroll
      for (int r = 0; r < 4; ++r)
        redl[wc][wr * 64 + mi * 16 + fr + r] = rsum[mi][r];
  }
  __syncthreads();
  if (wc == 0 && (l & 15) == 0) {
#pragma unroll
    for (int mi = 0; mi < 4; ++mi)
#pragma unroll
      for (int r = 0; r < 4; ++r) {
        int row_l = wr * 64 + mi * 16 + fr + r;
        int gq = qt * 128 + row_l;
        mT[((size_t)b * 16 + kt) * SS + gq] = mtv[mi][r];
        lT[((size_t)b * 16 + kt) * SS + gq] =
            redl[0][row_l] + redl[1][row_l] + redl[2][row_l] + redl[3][row_l];
      }
  }
  // write provisional P tile (bf16)
  unsigned short* Pp = P + (size_t)b * SS * SS;
#pragma unroll
  for (int mi = 0; mi < 4; ++mi)
#pragma unroll
    for (int ni = 0; ni < 2; ++ni) {
      int gc = kt * 128 + wc * 32 + ni * 16 + fc;
#pragma unroll
      for (int r = 0; r < 4; ++r) {
        int gr = qt * 128 + wr * 64 + mi * 16 + fr + r;
        Pp[(size_t)gr * SS + gc] = f2bf(acc[mi][ni][r]);
      }
    }
}

// ---- combine tile stats -> fixup factors F = exp(m_t - m)/l (into mT) -----
__global__ __launch_bounds__(256) void k_combine(float* __restrict__ mT,
                                                 const float* __restrict__ lT) {
  const int idx = blockIdx.x * 256 + threadIdx.x;  // 0..8191
  const int b = idx >> 11, q = idx & 2047;
  const int qt = q >> 7;
  float mv[16];
  float m = -INFINITY;
#pragma unroll
  for (int kt = 0; kt < 16; ++kt)
    if (kt <= qt) {
      mv[kt] = mT[((size_t)b * 16 + kt) * SS + q];
      m = fmaxf(m, mv[kt]);
    }
  float lsum = 0.f;
#pragma unroll
  for (int kt = 0; kt < 16; ++kt)
    if (kt <= qt) lsum += lT[((size_t)b * 16 + kt) * SS + q] * __expf(mv[kt] - m);
  const float inv = 1.f / lsum;
#pragma unroll
  for (int kt = 0; kt < 16; ++kt)
    if (kt <= qt) mT[((size_t)b * 16 + kt) * SS + q] = __expf(mv[kt] - m) * inv;
}

// ---- PV with F fold: out[q][d] = sum_kt F[kt][q] * (P_kt[q,:] . V[:,d]) ---
// 2-phase double-buffered over flattened 32-K steps; fold every 4 steps.
__global__ __launch_bounds__(512, 4) void k_pv(
    const unsigned short* __restrict__ P,
    const unsigned short* __restrict__ vt,
    const float* __restrict__ F, float* __restrict__ out) {
  __shared__ unsigned short As[8192], Bs[8192];
  __shared__ float Flds[2048];
  const int b = blockIdx.z;
  const int n0 = blockIdx.x * 128;        // d
  const int qt = 15 - blockIdx.y;         // heavy tiles dispatched first
  const int m0 = qt * 128;                // q
  const int nsteps = (qt + 1) * 4;        // 32-wide K steps
  const int t = threadIdx.x, l = t & 63, w = t >> 6, wr = w >> 2, wc = w & 3;
  const int fr = (l >> 4) * 4, fc = l & 15;
  // preload F[kt][local row] for kt <= qt (covered by prologue __syncthreads)
  for (int idx = t; idx < (qt + 1) * 128; idx += 512)
    Flds[idx] = F[((size_t)b * 16 + (idx >> 7)) * SS + m0 + (idx & 127)];
  f32x4 accO[4][2], accP[4][2];
#pragma unroll
  for (int i = 0; i < 4; ++i)
#pragma unroll
    for (int j = 0; j < 2; ++j) {
      accO[i][j] = f32x4{0.f, 0.f, 0.f, 0.f};
      accP[i][j] = f32x4{0.f, 0.f, 0.f, 0.f};
    }
  const unsigned short* Pp = P + (size_t)b * SS * SS;
  const unsigned short* Vp = vt + (size_t)b * DD * SS;
  const int srow = t >> 2, scol = (t & 3) * 8;
  const unsigned short* ga = Pp + (size_t)(m0 + srow) * SS + scol;
  const unsigned short* gb = Vp + (size_t)(n0 + srow) * SS + scol;
  unsigned short* la = As + t * 8;
  unsigned short* lb = Bs + t * 8;
  const int aoff = (wr * 64 + (l & 15)) * 32 + (l >> 4) * 8;
  const int boff = (wc * 32 + (l & 15)) * 32 + (l >> 4) * 8;
  // prologue: stage step 0 into buffer 0
  gload16(ga, la);
  gload16(gb, lb);
  __syncthreads();
  int cur = 0;
  for (int i = 0; i < nsteps; ++i) {
    if (i + 1 < nsteps) {
      const int kk = (i + 1) << 5;
      gload16(ga + kk, la + (cur ^ 1) * 4096);
      gload16(gb + kk, lb + (cur ^ 1) * 4096);
    }
    const unsigned short* Ab = As + cur * 4096;
    const unsigned short* Bb = Bs + cur * 4096;
    bf16x8 av[4], bv[2];
#pragma unroll
    for (int ii = 0; ii < 4; ++ii) av[ii] = *(const bf16x8*)(Ab + aoff + ii * 512);
#pragma unroll
    for (int ii = 0; ii < 2; ++ii) bv[ii] = *(const bf16x8*)(Bb + boff + ii * 512);
#pragma unroll
    for (int mi = 0; mi < 4; ++mi)
#pragma unroll
      for (int ni = 0; ni < 2; ++ni)
        accP[mi][ni] = __builtin_amdgcn_mfma_f32_16x16x32_bf16(
            av[mi], bv[ni], accP[mi][ni], 0, 0, 0);
    if ((i & 3) == 3) {  // fold chunk (kt = i>>2) with per-row factor F
      const int c = i >> 2;
#pragma unroll
      for (int mi = 0; mi < 4; ++mi)
#pragma unroll
        for (int r = 0; r < 4; ++r) {
          const float f = Flds[c * 128 + wr * 64 + mi * 16 + fr + r];
#pragma unroll
          for (int ni = 0; ni < 2; ++ni) {
            accO[mi][ni][r] += f * accP[mi][ni][r];
            accP[mi][ni][r] = 0.f;
          }
        }
    }
    __syncthreads();
    cur ^= 1;
  }
  float* O = out + (size_t)b * SS * DD;
#pragma unroll
  for (int mi = 0; mi < 4; ++mi)
#pragma unroll
    for (int ni = 0; ni < 2; ++ni) {
      int gc = n0 + wc * 32 + ni * 16 + fc;
#pragma unroll
      for (int r = 0; r < 4; ++r) {
        int gr = m0 + wr * 64 + mi * 16 + fr + r;
        O[(size_t)gr * DD + gc] = accO[mi][ni][r];
      }
    }
}

// ---------------------------------------------------------------------------
extern "C" void kernel_launch(void* const* d_in, const int* in_sizes, int n_in,
                              void* d_out, int out_size, void* d_ws, size_t ws_size,
                              hipStream_t stream) {
  (void)in_sizes; (void)n_in; (void)out_size; (void)ws_size;
  const float* x  = (const float*)d_in[0];
  const float* Wq = (const float*)d_in[1];
  const float* bq = (const float*)d_in[2];
  const float* Wk = (const float*)d_in[3];
  const float* bk = (const float*)d_in[4];
  const float* Wv = (const float*)d_in[5];
  const float* bv = (const float*)d_in[6];
  float* out = (float*)d_out;

  char* w = (char*)d_ws;
  // workspace layout (bytes)
  unsigned short* xb  = (unsigned short*)(w + 0);           // 16 MB  x bf16
  unsigned short* Wt  = (unsigned short*)(w + 16777216);    // 6 MB   Wq^T,Wk^T,Wv^T bf16
  unsigned short* qb  = (unsigned short*)(w + 23068672);    // 16 MB  Q bf16
  unsigned short* kb  = (unsigned short*)(w + 39845888);    // 16 MB  K bf16
  unsigned short* vt  = (unsigned short*)(w + 56623104);    // 16 MB  V^T bf16
  unsigned short* P   = (unsigned short*)(w + 73400320);    // 32 MB  attn probs bf16
  float*          mT  = (float*)(w + 106954752);            // 0.5 MB tile max -> fixup F
  float*          lT  = (float*)(w + 107479040);            // 0.5 MB tile sumexp
  unsigned short* Wqt = Wt;
  unsigned short* Wkt = Wt + (size_t)DD * DD;
  unsigned short* Wvt = Wt + (size_t)2 * DD * DD;

  // 1) conversions
  k_conv_x<<<dim3(8192), dim3(256), 0, stream>>>(x, xb);
  k_prep_w<<<dim3(16, 16, 3), dim3(256), 0, stream>>>(Wq, Wk, Wv, Wt);
  // 2) Q, K projections
  k_qk_gemm<<<dim3(64, 8, 2), dim3(512), 0, stream>>>(xb, Wqt, Wkt, bq, bk, qb, kb);
  // 3) V^T projection
  k_vt_gemm<<<dim3(8, 16, 4), dim3(512), 0, stream>>>(Wvt, xb, bv, vt);
  // 4) causal scores + tile softmax (triangular-compacted grid: 136 pairs)
  k_scores<<<dim3(136, 1, 4), dim3(512), 0, stream>>>(qb, kb, P, mT, lT);
  // 5) combine stats -> F
  k_combine<<<dim3(32), dim3(256), 0, stream>>>(mT, lT);
  // 6) PV with F fold -> output
  k_pv<<<dim3(8, 16, 4), dim3(512), 0, stream>>>(P, vt, mT, out);
}

// Round 13
// 287.473 us; speedup vs baseline: 1.0362x; 1.0362x over previous
//
#include <hip/hip_runtime.h>
#include <cstdint>
#include <cstddef>

// ---------------------------------------------------------------------------
// SelfAttention (B=4, S=2048, D=1024, single head, causal) on gfx950.
// Round 11/12/13: m230-verified 2-phase pipeline: per K-step {stage(t+1)->
// buf^1; ds_read+MFMA buf[cur]; vmcnt(0)+s_barrier} -- stage hides under
// compute, ONE barrier per step. k_scores grid 136 pairs (Round-8..10 bug:
// 544 launched 4x the triangle -> OOB writes -> NaN). T1 chunked XCD swizzle
// on all GEMM grids (136=8*17, 1024=8*128, 512=8*64 all exact).
// Pipeline: conv -> Q,K GEMM -> V^T GEMM -> tile-softmax scores -> combine
// -> PV GEMM (with F fold) -> out.
// ---------------------------------------------------------------------------

typedef __attribute__((ext_vector_type(8))) __bf16 bf16x8;
typedef __attribute__((ext_vector_type(4))) float f32x4;
typedef __attribute__((ext_vector_type(4))) float float4v;
typedef __attribute__((ext_vector_type(8))) unsigned short u16x8;
typedef __attribute__((ext_vector_type(4))) unsigned short u16x4;

#define DEVI static __device__ __forceinline__

static constexpr int SS = 2048;
static constexpr int DD = 1024;
static constexpr float SCALE = 0.03125f;  // 1/sqrt(1024)

DEVI unsigned short f2bf(float f) {
  unsigned int u = __builtin_bit_cast(unsigned int, f);
  u += 0x7fffu + ((u >> 16) & 1u);  // RNE
  return (unsigned short)(u >> 16);
}
DEVI float bf2f(unsigned short h) {
  unsigned int u = ((unsigned int)h) << 16;
  return __builtin_bit_cast(float, u);
}

DEVI void gload16(const void* g, void* l) {
  __builtin_amdgcn_global_load_lds(
      (const __attribute__((address_space(1))) unsigned int*)g,
      (__attribute__((address_space(3))) unsigned int*)l, 16, 0, 0);
}

// raw barrier with compiler memory fence (prevents LDS-op reordering across)
#define BARRIER_MEM() asm volatile("s_barrier" ::: "memory")
#define WAITCNT_VM0() asm volatile("s_waitcnt vmcnt(0)" ::: "memory")
#define WAITCNT_LGKM0() asm volatile("s_waitcnt lgkmcnt(0)" ::: "memory")

// ---- m230-form 2-phase double-buffered 128x128 GEMM, 512 thr / 8 waves ----
// C += A[M,K] * Bt[N,K]^T, bf16 in, f32 acc. Wave tile 64x32 -> acc[4][2].
// As/Bs: 8192 shorts each (two 4096-short buffers). K multiple of 32.
// Per step: stage(t+1) FIRST, then ds_read+MFMA(t), then vmcnt(0)+barrier
// (prefetch landed AND reads consumed) -- stage latency hides under compute.
DEVI void gemm2p(const unsigned short* __restrict__ A,
                 const unsigned short* __restrict__ Bt,
                 int lda, int ldb, int m0, int n0, int K,
                 unsigned short* As, unsigned short* Bs,
                 f32x4 acc[4][2]) {
  const int t = threadIdx.x;
  const int l = t & 63, w = t >> 6;
  const int wr = w >> 2, wc = w & 3;
  const int srow = t >> 2;          // staging row 0..127
  const int scol = (t & 3) * 8;     // staging col offset (elems)
  const unsigned short* ga = A + (size_t)(m0 + srow) * lda + scol;
  const unsigned short* gb = Bt + (size_t)(n0 + srow) * ldb + scol;
  unsigned short* la = As + t * 8;  // linear LDS dest (wave-uniform + lane*16B)
  unsigned short* lb = Bs + t * 8;
  const int aoff = (wr * 64 + (l & 15)) * 32 + (l >> 4) * 8;
  const int boff = (wc * 32 + (l & 15)) * 32 + (l >> 4) * 8;
  const int nt = K >> 5;
  // prologue: stage tile 0 into buffer 0
  gload16(ga, la);
  gload16(gb, lb);
  WAITCNT_VM0();
  BARRIER_MEM();
  int cur = 0;
  for (int ti = 0; ti < nt; ++ti) {
    if (ti + 1 < nt) {              // issue next-tile stage BEFORE compute
      const int kk = (ti + 1) << 5;
      gload16(ga + kk, la + (cur ^ 1) * 4096);
      gload16(gb + kk, lb + (cur ^ 1) * 4096);
    }
    const unsigned short* Ab = As + cur * 4096;
    const unsigned short* Bb = Bs + cur * 4096;
    bf16x8 av[4], bv[2];
#pragma unroll
    for (int i = 0; i < 4; ++i) av[i] = *(const bf16x8*)(Ab + aoff + i * 512);
#pragma unroll
    for (int i = 0; i < 2; ++i) bv[i] = *(const bf16x8*)(Bb + boff + i * 512);
#pragma unroll
    for (int mi = 0; mi < 4; ++mi)
#pragma unroll
      for (int ni = 0; ni < 2; ++ni)
        acc[mi][ni] = __builtin_amdgcn_mfma_f32_16x16x32_bf16(
            av[mi], bv[ni], acc[mi][ni], 0, 0, 0);
    WAITCNT_VM0();                  // prefetch landed (mostly hidden by MFMA)
    BARRIER_MEM();                  // + all waves' reads of buf[cur] consumed
    cur ^= 1;
  }
}

// ---- prep: x fp32 -> bf16 -------------------------------------------------
__global__ __launch_bounds__(256) void k_conv_x(const float* __restrict__ x,
                                                unsigned short* __restrict__ xb) {
  size_t i = ((size_t)blockIdx.x * 256 + threadIdx.x) * 4;
  float4v v = *(const float4v*)(x + i);
  u16x4 o;
#pragma unroll
  for (int j = 0; j < 4; ++j) o[j] = f2bf(v[j]);
  *(u16x4*)(xb + i) = o;
}

// ---- prep: W [k][n] fp32 -> Wt [n][k] bf16 (3 matrices) -------------------
__global__ __launch_bounds__(256) void k_prep_w(const float* __restrict__ Wq,
                                                const float* __restrict__ Wk,
                                                const float* __restrict__ Wv,
                                                unsigned short* __restrict__ Wt) {
  const int z = blockIdx.z;
  const float* W = (z == 0) ? Wq : (z == 1) ? Wk : Wv;
  unsigned short* O = Wt + (size_t)z * DD * DD;
  const int c0 = blockIdx.x * 64, r0 = blockIdx.y * 64;
  __shared__ unsigned short T[64][72];
  const int t = threadIdx.x;
#pragma unroll
  for (int i = 0; i < 4; ++i) {
    int idx = t + i * 256;          // 0..1023
    int row = idx >> 4;             // 0..63
    int c4 = (idx & 15) * 4;
    float4v v = *(const float4v*)(W + (size_t)(r0 + row) * DD + c0 + c4);
#pragma unroll
    for (int j = 0; j < 4; ++j) T[row][c4 + j] = f2bf(v[j]);
  }
  __syncthreads();
#pragma unroll
  for (int i = 0; i < 2; ++i) {
    int idx = t + i * 256;          // 0..511
    int n = idx >> 3;               // 0..63
    int g = (idx & 7) * 8;          // k group
    u16x8 u;
#pragma unroll
    for (int j = 0; j < 8; ++j) u[j] = T[g + j][n];
    *(u16x8*)(O + (size_t)(c0 + n) * DD + r0 + g) = u;
  }
}

// ---- Q and K projections: C[m][n] = x[m][:]*Wt[n][:] + bias[n] ------------
// XCD swizzle: flat 1024 blocks -> chunks of 128 per XCD (same weight panels)
__global__ __launch_bounds__(512, 4) void k_qk_gemm(
    const unsigned short* __restrict__ xb,
    const unsigned short* __restrict__ Wqt,
    const unsigned short* __restrict__ Wkt,
    const float* __restrict__ bq, const float* __restrict__ bk,
    unsigned short* __restrict__ qb, unsigned short* __restrict__ kb) {
  __shared__ unsigned short As[8192], Bs[8192];
  const int flat0 = blockIdx.x + 64 * blockIdx.y + 512 * blockIdx.z;
  const int flat = (flat0 & 7) * 128 + (flat0 >> 3);   // bijective (1024=8*128)
  const int bx = flat & 63, by = (flat >> 6) & 7, z = flat >> 9;
  const unsigned short* Bt = z ? Wkt : Wqt;
  const float* bias = z ? bk : bq;
  unsigned short* C = z ? kb : qb;
  const int m0 = bx * 128, n0 = by * 128;
  f32x4 acc[4][2];
#pragma unroll
  for (int i = 0; i < 4; ++i)
#pragma unroll
    for (int j = 0; j < 2; ++j) acc[i][j] = f32x4{0.f, 0.f, 0.f, 0.f};
  gemm2p(xb, Bt, DD, DD, m0, n0, DD, As, Bs, acc);
  const int t = threadIdx.x, l = t & 63, w = t >> 6, wr = w >> 2, wc = w & 3;
  const int fr = (l >> 4) * 4, fc = l & 15;
#pragma unroll
  for (int mi = 0; mi < 4; ++mi)
#pragma unroll
    for (int ni = 0; ni < 2; ++ni) {
      int gc = n0 + wc * 32 + ni * 16 + fc;
      float bv_ = bias[gc];
#pragma unroll
      for (int r = 0; r < 4; ++r) {
        int gr = m0 + wr * 64 + mi * 16 + fr + r;
        C[(size_t)gr * DD + gc] = f2bf(acc[mi][ni][r] + bv_);
      }
    }
}

// ---- V^T: C[d][s] = Wvt[d][:] * x[b][s][:] + bv[d]  (per batch) -----------
__global__ __launch_bounds__(512, 4) void k_vt_gemm(
    const unsigned short* __restrict__ Wvt,
    const unsigned short* __restrict__ xb,
    const float* __restrict__ bv, unsigned short* __restrict__ vt) {
  __shared__ unsigned short As[8192], Bs[8192];
  const int flat0 = blockIdx.x + 8 * blockIdx.y + 128 * blockIdx.z;
  const int flat = (flat0 & 7) * 64 + (flat0 >> 3);    // bijective (512=8*64)
  const int bx = flat & 7, by = (flat >> 3) & 15, b = flat >> 7;
  const int m0 = bx * 128;  // d
  const int n0 = by * 128;  // s
  f32x4 acc[4][2];
#pragma unroll
  for (int i = 0; i < 4; ++i)
#pragma unroll
    for (int j = 0; j < 2; ++j) acc[i][j] = f32x4{0.f, 0.f, 0.f, 0.f};
  gemm2p(Wvt, xb + (size_t)b * SS * DD, DD, DD, m0, n0, DD, As, Bs, acc);
  unsigned short* C = vt + (size_t)b * DD * SS;
  const int t = threadIdx.x, l = t & 63, w = t >> 6, wr = w >> 2, wc = w & 3;
  const int fr = (l >> 4) * 4, fc = l & 15;
#pragma unroll
  for (int mi = 0; mi < 4; ++mi)
#pragma unroll
    for (int ni = 0; ni < 2; ++ni) {
      int gc = n0 + wc * 32 + ni * 16 + fc;
#pragma unroll
      for (int r = 0; r < 4; ++r) {
        int gr = m0 + wr * 64 + mi * 16 + fr + r;
        C[(size_t)gr * SS + gc] = f2bf(acc[mi][ni][r] + bv[gr]);
      }
    }
}

// ---- scores: per (q-tile,k-tile), S=QK^T*scale, causal mask, tile softmax -
// Triangular grid: 136 pairs (16*17/2), XCD-chunked (136 = 8*17 exact).
// writes P_prov = exp(s - m_tile) (bf16) and per-row (m_tile, l_tile).
__global__ __launch_bounds__(512, 4) void k_scores(
    const unsigned short* __restrict__ qb,
    const unsigned short* __restrict__ kb,
    unsigned short* __restrict__ P,
    float* __restrict__ mT, float* __restrict__ lT) {
  const int praw = blockIdx.x, b = blockIdx.z;
  const int p = (praw & 7) * 17 + (praw >> 3);         // bijective (136=8*17)
  int qt = (int)((sqrtf(8.f * (float)p + 1.f) - 1.f) * 0.5f);
  while ((qt + 1) * (qt + 2) / 2 <= p) ++qt;
  while (qt * (qt + 1) / 2 > p) --qt;
  const int kt = p - qt * (qt + 1) / 2;                // 0 <= kt <= qt <= 15
  __shared__ unsigned short As[8192], Bs[8192];
  __shared__ float redm[4][128];
  __shared__ float redl[4][128];
  f32x4 acc[4][2];
#pragma unroll
  for (int i = 0; i < 4; ++i)
#pragma unroll
    for (int j = 0; j < 2; ++j) acc[i][j] = f32x4{0.f, 0.f, 0.f, 0.f};
  const unsigned short* qp = qb + (size_t)b * SS * DD;
  const unsigned short* kp = kb + (size_t)b * SS * DD;
  gemm2p(qp, kp, DD, DD, qt * 128, kt * 128, DD, As, Bs, acc);

  const int t = threadIdx.x, l = t & 63, w = t >> 6, wr = w >> 2, wc = w & 3;
  const int fr = (l >> 4) * 4, fc = l & 15;
  const bool diag = (kt == qt);
  // scale + causal mask in place (local coords suffice: tiles share offset)
#pragma unroll
  for (int mi = 0; mi < 4; ++mi)
#pragma unroll
    for (int ni = 0; ni < 2; ++ni) {
      int lc = wc * 32 + ni * 16 + fc;
#pragma unroll
      for (int r = 0; r < 4; ++r) {
        int lr = wr * 64 + mi * 16 + fr + r;
        float s = acc[mi][ni][r] * SCALE;
        if (diag && lc > lr) s = -INFINITY;
        acc[mi][ni][r] = s;
      }
    }
  // per-row tile max across this wave's 32-col slice
  float rmax[4][4];
#pragma unroll
  for (int mi = 0; mi < 4; ++mi)
#pragma unroll
    for (int r = 0; r < 4; ++r)
      rmax[mi][r] = fmaxf(acc[mi][0][r], acc[mi][1][r]);
#pragma unroll
  for (int d = 1; d < 16; d <<= 1)
#pragma unroll
    for (int mi = 0; mi < 4; ++mi)
#pragma unroll
      for (int r = 0; r < 4; ++r)
        rmax[mi][r] = fmaxf(rmax[mi][r], __shfl_xor(rmax[mi][r], d));
  if ((l & 15) == 0) {
#pragma unroll
    for (int mi = 0; mi < 4; ++mi)
#pragma unroll
      for (int r = 0; r < 4; ++r)
        redm[wc][wr * 64 + mi * 16 + fr + r] = rmax[mi][r];
  }
  __syncthreads();
  float mtv[4][4];
#pragma unroll
  for (int mi = 0; mi < 4; ++mi)
#pragma unroll
    for (int r = 0; r < 4; ++r) {
      int row_l = wr * 64 + mi * 16 + fr + r;
      mtv[mi][r] = fmaxf(fmaxf(redm[0][row_l], redm[1][row_l]),
                         fmaxf(redm[2][row_l], redm[3][row_l]));
    }
  // P = exp(s - m_tile), row sums
  float rsum[4][4];
#pragma unroll
  for (int mi = 0; mi < 4; ++mi)
#pragma unroll
    for (int ni = 0; ni < 2; ++ni)
#pragma unroll
      for (int r = 0; r < 4; ++r) {
        float pv = __expf(acc[mi][ni][r] - mtv[mi][r]);
        acc[mi][ni][r] = pv;
        if (ni == 0) rsum[mi][r] = pv; else rsum[mi][r] += pv;
      }
#pragma unroll
  for (int d = 1; d < 16; d <<= 1)
#pragma unroll
    for (int mi = 0; mi < 4; ++mi)
#pragma unroll
      for (int r = 0; r < 4; ++r)
        rsum[mi][r] += __shfl_xor(rsum[mi][r], d);
  if ((l & 15) == 0) {
#pragma unroll
    for (int mi = 0; mi < 4; ++mi)
#pragma unroll
      for (int r = 0; r < 4; ++r)
        redl[wc][wr * 64 + mi * 16 + fr + r] = rsum[mi][r];
  }
  __syncthreads();
  if (wc == 0 && (l & 15) == 0) {
#pragma unroll
    for (int mi = 0; mi < 4; ++mi)
#pragma unroll
      for (int r = 0; r < 4; ++r) {
        int row_l = wr * 64 + mi * 16 + fr + r;
        int gq = qt * 128 + row_l;
        mT[((size_t)b * 16 + kt) * SS + gq] = mtv[mi][r];
        lT[((size_t)b * 16 + kt) * SS + gq] =
            redl[0][row_l] + redl[1][row_l] + redl[2][row_l] + redl[3][row_l];
      }
  }
  // write provisional P tile (bf16)
  unsigned short* Pp = P + (size_t)b * SS * SS;
#pragma unroll
  for (int mi = 0; mi < 4; ++mi)
#pragma unroll
    for (int ni = 0; ni < 2; ++ni) {
      int gc = kt * 128 + wc * 32 + ni * 16 + fc;
#pragma unroll
      for (int r = 0; r < 4; ++r) {
        int gr = qt * 128 + wr * 64 + mi * 16 + fr + r;
        Pp[(size_t)gr * SS + gc] = f2bf(acc[mi][ni][r]);
      }
    }
}

// ---- combine tile stats -> fixup factors F = exp(m_t - m)/l (into mT) -----
__global__ __launch_bounds__(256) void k_combine(float* __restrict__ mT,
                                                 const float* __restrict__ lT) {
  const int idx = blockIdx.x * 256 + threadIdx.x;  // 0..8191
  const int b = idx >> 11, q = idx & 2047;
  const int qt = q >> 7;
  float mv[16];
  float m = -INFINITY;
#pragma unroll
  for (int kt = 0; kt < 16; ++kt)
    if (kt <= qt) {
      mv[kt] = mT[((size_t)b * 16 + kt) * SS + q];
      m = fmaxf(m, mv[kt]);
    }
  float lsum = 0.f;
#pragma unroll
  for (int kt = 0; kt < 16; ++kt)
    if (kt <= qt) lsum += lT[((size_t)b * 16 + kt) * SS + q] * __expf(mv[kt] - m);
  const float inv = 1.f / lsum;
#pragma unroll
  for (int kt = 0; kt < 16; ++kt)
    if (kt <= qt) mT[((size_t)b * 16 + kt) * SS + q] = __expf(mv[kt] - m) * inv;
}

// ---- PV with F fold: out[q][d] = sum_kt F[kt][q] * (P_kt[q,:] . V[:,d]) ---
// m230-form 2-phase over flattened 32-K steps; fold every 4 steps.
__global__ __launch_bounds__(512, 4) void k_pv(
    const unsigned short* __restrict__ P,
    const unsigned short* __restrict__ vt,
    const float* __restrict__ F, float* __restrict__ out) {
  __shared__ unsigned short As[8192], Bs[8192];
  __shared__ float Flds[2048];
  const int flat0 = blockIdx.x + 8 * blockIdx.y + 128 * blockIdx.z;
  const int flat = (flat0 & 7) * 64 + (flat0 >> 3);    // bijective (512=8*64)
  const int bx = flat & 7, by = (flat >> 3) & 15, b = flat >> 7;
  const int n0 = bx * 128;                // d
  const int qt = 15 - by;                 // heavy tiles dispatched first
  const int m0 = qt * 128;                // q
  const int nsteps = (qt + 1) * 4;        // 32-wide K steps
  const int t = threadIdx.x, l = t & 63, w = t >> 6, wr = w >> 2, wc = w & 3;
  const int fr = (l >> 4) * 4, fc = l & 15;
  // preload F[kt][local row] for kt <= qt
  for (int idx = t; idx < (qt + 1) * 128; idx += 512)
    Flds[idx] = F[((size_t)b * 16 + (idx >> 7)) * SS + m0 + (idx & 127)];
  WAITCNT_LGKM0();                        // Flds ds_writes committed
  f32x4 accO[4][2], accP[4][2];
#pragma unroll
  for (int i = 0; i < 4; ++i)
#pragma unroll
    for (int j = 0; j < 2; ++j) {
      accO[i][j] = f32x4{0.f, 0.f, 0.f, 0.f};
      accP[i][j] = f32x4{0.f, 0.f, 0.f, 0.f};
    }
  const unsigned short* Pp = P + (size_t)b * SS * SS;
  const unsigned short* Vp = vt + (size_t)b * DD * SS;
  const int srow = t >> 2, scol = (t & 3) * 8;
  const unsigned short* ga = Pp + (size_t)(m0 + srow) * SS + scol;
  const unsigned short* gb = Vp + (size_t)(n0 + srow) * SS + scol;
  unsigned short* la = As + t * 8;
  unsigned short* lb = Bs + t * 8;
  const int aoff = (wr * 64 + (l & 15)) * 32 + (l >> 4) * 8;
  const int boff = (wc * 32 + (l & 15)) * 32 + (l >> 4) * 8;
  // prologue: stage step 0 into buffer 0
  gload16(ga, la);
  gload16(gb, lb);
  WAITCNT_VM0();
  BARRIER_MEM();
  int cur = 0;
  for (int i = 0; i < nsteps; ++i) {
    if (i + 1 < nsteps) {                 // issue next stage BEFORE compute
      const int kk = (i + 1) << 5;
      gload16(ga + kk, la + (cur ^ 1) * 4096);
      gload16(gb + kk, lb + (cur ^ 1) * 4096);
    }
    const unsigned short* Ab = As + cur * 4096;
    const unsigned short* Bb = Bs + cur * 4096;
    bf16x8 av[4], bv[2];
#pragma unroll
    for (int j = 0; j < 4; ++j) av[j] = *(const bf16x8*)(Ab + aoff + j * 512);
#pragma unroll
    for (int j = 0; j < 2; ++j) bv[j] = *(const bf16x8*)(Bb + boff + j * 512);
#pragma unroll
    for (int mi = 0; mi < 4; ++mi)
#pragma unroll
      for (int ni = 0; ni < 2; ++ni)
        accP[mi][ni] = __builtin_amdgcn_mfma_f32_16x16x32_bf16(
            av[mi], bv[ni], accP[mi][ni], 0, 0, 0);
    if ((i & 3) == 3) {  // fold chunk (kt = i>>2) with per-row factor F
      const int c = i >> 2;
#pragma unroll
      for (int mi = 0; mi < 4; ++mi)
#pragma unroll
        for (int r = 0; r < 4; ++r) {
          const float f = Flds[c * 128 + wr * 64 + mi * 16 + fr + r];
#pragma unroll
          for (int ni = 0; ni < 2; ++ni) {
            accO[mi][ni][r] += f * accP[mi][ni][r];
            accP[mi][ni][r] = 0.f;
          }
        }
    }
    WAITCNT_VM0();
    BARRIER_MEM();
    cur ^= 1;
  }
  float* O = out + (size_t)b * SS * DD;
#pragma unroll
  for (int mi = 0; mi < 4; ++mi)
#pragma unroll
    for (int ni = 0; ni < 2; ++ni) {
      int gc = n0 + wc * 32 + ni * 16 + fc;
#pragma unroll
      for (int r = 0; r < 4; ++r) {
        int gr = m0 + wr * 64 + mi * 16 + fr + r;
        O[(size_t)gr * DD + gc] = accO[mi][ni][r];
      }
    }
}

// ---------------------------------------------------------------------------
extern "C" void kernel_launch(void* const* d_in, const int* in_sizes, int n_in,
                              void* d_out, int out_size, void* d_ws, size_t ws_size,
                              hipStream_t stream) {
  (void)in_sizes; (void)n_in; (void)out_size; (void)ws_size;
  const float* x  = (const float*)d_in[0];
  const float* Wq = (const float*)d_in[1];
  const float* bq = (const float*)d_in[2];
  const float* Wk = (const float*)d_in[3];
  const float* bk = (const float*)d_in[4];
  const float* Wv = (const float*)d_in[5];
  const float* bv = (const float*)d_in[6];
  float* out = (float*)d_out;

  char* w = (char*)d_ws;
  // workspace layout (bytes)
  unsigned short* xb  = (unsigned short*)(w + 0);           // 16 MB  x bf16
  unsigned short* Wt  = (unsigned short*)(w + 16777216);    // 6 MB   Wq^T,Wk^T,Wv^T bf16
  unsigned short* qb  = (unsigned short*)(w + 23068672);    // 16 MB  Q bf16
  unsigned short* kb  = (unsigned short*)(w + 39845888);    // 16 MB  K bf16
  unsigned short* vt  = (unsigned short*)(w + 56623104);    // 16 MB  V^T bf16
  unsigned short* P   = (unsigned short*)(w + 73400320);    // 32 MB  attn probs bf16
  float*          mT  = (float*)(w + 106954752);            // 0.5 MB tile max -> fixup F
  float*          lT  = (float*)(w + 107479040);            // 0.5 MB tile sumexp
  unsigned short* Wqt = Wt;
  unsigned short* Wkt = Wt + (size_t)DD * DD;
  unsigned short* Wvt = Wt + (size_t)2 * DD * DD;

  // 1) conversions
  k_conv_x<<<dim3(8192), dim3(256), 0, stream>>>(x, xb);
  k_prep_w<<<dim3(16, 16, 3), dim3(256), 0, stream>>>(Wq, Wk, Wv, Wt);
  // 2) Q, K projections
  k_qk_gemm<<<dim3(64, 8, 2), dim3(512), 0, stream>>>(xb, Wqt, Wkt, bq, bk, qb, kb);
  // 3) V^T projection
  k_vt_gemm<<<dim3(8, 16, 4), dim3(512), 0, stream>>>(Wvt, xb, bv, vt);
  // 4) causal scores + tile softmax (136 triangular pairs, XCD-chunked)
  k_scores<<<dim3(136, 1, 4), dim3(512), 0, stream>>>(qb, kb, P, mT, lT);
  // 5) combine stats -> F
  k_combine<<<dim3(32), dim3(256), 0, stream>>>(mT, lT);
  // 6) PV with F fold -> output
  k_pv<<<dim3(8, 16, 4), dim3(512), 0, stream>>>(P, vt, mT, out);
}